// Round 3
// baseline (4755.468 us; speedup 1.0000x reference)
//
#include <hip/hip_runtime.h>
#include <hip/hip_bf16.h>
#include <stdint.h>

#define DD 192
#define NSEQ 4096
#define NB 4
#define NEGV -1e9f
#define WOFF ((size_t)NB * NSEQ * DD)   // element offset of weights in d_out

// ---------------------------------------------------------------------------
// World (established rounds 0-2): ALL inputs fp32, d_out fp32,
// layout = out[4,4096,192] ++ weights[4,4096,4096].
// ---------------------------------------------------------------------------

// y[r][e] = sum_d x[r][d] * W[e][d]; fp32. block 192, 8 rows/block.
__global__ __launch_bounds__(192) void proj_kernel(
        const float* __restrict__ x, const float* __restrict__ W,
        float* __restrict__ y) {
    __shared__ float xs[8][DD];
    const int r0 = blockIdx.x * 8;
    const int t  = threadIdx.x;               // 0..191 = output column e
    for (int i = t; i < 8 * DD; i += 192)
        xs[i / DD][i % DD] = x[(size_t)r0 * DD + i];
    __syncthreads();

    float acc[8] = {0.f,0.f,0.f,0.f,0.f,0.f,0.f,0.f};
    const float* wrow = W + t * DD;
    #pragma unroll
    for (int c = 0; c < DD; c += 8) {
        float4 pa = *reinterpret_cast<const float4*>(wrow + c);
        float4 pb = *reinterpret_cast<const float4*>(wrow + c + 4);
        #pragma unroll
        for (int r = 0; r < 8; ++r) {
            const float* xr = &xs[r][c];
            acc[r] += pa.x*xr[0] + pa.y*xr[1] + pa.z*xr[2] + pa.w*xr[3]
                    + pb.x*xr[4] + pb.y*xr[5] + pb.z*xr[6] + pb.w*xr[7];
        }
    }
    #pragma unroll
    for (int r = 0; r < 8; ++r) y[(size_t)(r0 + r) * DD + t] = acc[r];
}

// logits = q k^T + bias + mask*NEG; softmax rows; write fp32 weights to d_out.
// grid (NSEQ/4, NB), block 256. Thread t handles k = j*256+t, j=0..15, 4 q-rows.
__global__ __launch_bounds__(256) void attn_softmax_kernel(
        const float* __restrict__ qws, const float* __restrict__ kws,
        const float* __restrict__ bias, const float* __restrict__ mask,
        float* __restrict__ dout) {
    const int b  = blockIdx.y;
    const int q0 = blockIdx.x * 4;
    const int t  = threadIdx.x;

    __shared__ float qs[4][DD];
    for (int i = t; i < 4 * DD; i += 256) {
        int r = i / DD, d = i % DD;
        qs[r][d] = qws[((size_t)(b * NSEQ + q0 + r)) * DD + d];
    }
    __syncthreads();

    float acc[4][16];
    #pragma unroll
    for (int r = 0; r < 4; ++r)
        #pragma unroll
        for (int j = 0; j < 16; ++j) acc[r][j] = 0.f;

    const float* kb = kws + (size_t)b * NSEQ * DD;
    for (int c = 0; c < DD; c += 4) {
        float4 qv[4];
        #pragma unroll
        for (int r = 0; r < 4; ++r) qv[r] = *reinterpret_cast<const float4*>(&qs[r][c]);
        #pragma unroll
        for (int j = 0; j < 16; ++j) {
            const float4 kv = *reinterpret_cast<const float4*>(&kb[(size_t)(j * 256 + t) * DD + c]);
            #pragma unroll
            for (int r = 0; r < 4; ++r)
                acc[r][j] += qv[r].x * kv.x + qv[r].y * kv.y + qv[r].z * kv.z + qv[r].w * kv.w;
        }
    }

    const int lane = t & 63, wid = t >> 6;
    __shared__ float red[4][4];
    float pm[4];
    #pragma unroll
    for (int r = 0; r < 4; ++r) {
        const size_t rowoff = ((size_t)(b * NSEQ + q0 + r)) * NSEQ;
        float m = -3.4e38f;
        #pragma unroll
        for (int j = 0; j < 16; ++j) {
            const int kk = j * 256 + t;
            float l = acc[r][j] + bias[rowoff + kk] + mask[rowoff + kk] * NEGV;
            acc[r][j] = l;
            m = fmaxf(m, l);
        }
        pm[r] = m;
    }
    #pragma unroll
    for (int r = 0; r < 4; ++r) {
        float m = pm[r];
        for (int off = 32; off; off >>= 1) m = fmaxf(m, __shfl_down(m, off));
        if (lane == 0) red[r][wid] = m;
    }
    __syncthreads();
    float rowmax[4], psum[4];
    #pragma unroll
    for (int r = 0; r < 4; ++r)
        rowmax[r] = fmaxf(fmaxf(red[r][0], red[r][1]), fmaxf(red[r][2], red[r][3]));
    #pragma unroll
    for (int r = 0; r < 4; ++r) {
        float s = 0.f;
        #pragma unroll
        for (int j = 0; j < 16; ++j) {
            float e = __expf(acc[r][j] - rowmax[r]);
            acc[r][j] = e;
            s += e;
        }
        psum[r] = s;
    }
    __syncthreads();   // done reading red (maxes) before overwrite
    #pragma unroll
    for (int r = 0; r < 4; ++r) {
        float s = psum[r];
        for (int off = 32; off; off >>= 1) s += __shfl_down(s, off);
        if (lane == 0) red[r][wid] = s;
    }
    __syncthreads();
    float* wout = dout + WOFF;
    #pragma unroll
    for (int r = 0; r < 4; ++r) {
        const float inv = 1.0f / (red[r][0] + red[r][1] + red[r][2] + red[r][3]);
        const size_t rowoff = ((size_t)(b * NSEQ + q0 + r)) * NSEQ;
        #pragma unroll
        for (int j = 0; j < 16; ++j)
            wout[rowoff + j * 256 + t] = acc[r][j] * inv;
    }
}

// mid[q][e] = sum_k w[q][k] * v[k][e]; fp32 weights read back from d_out.
// grid (NSEQ/8, NB), block 64. Thread: e in {t, t+64, t+128}, 8 q-rows.
__global__ __launch_bounds__(64) void pv_kernel(
        const float* __restrict__ dout, const float* __restrict__ vws,
        float* __restrict__ mid) {
    const int b  = blockIdx.y;
    const int q0 = blockIdx.x * 8;
    const int t  = threadIdx.x;

    __shared__ float wsh[8][256];   // 8 KB
    float acc[8][3];
    #pragma unroll
    for (int r = 0; r < 8; ++r) { acc[r][0] = 0.f; acc[r][1] = 0.f; acc[r][2] = 0.f; }

    const float* wts = dout + WOFF;
    const float* vb  = vws + (size_t)b * NSEQ * DD;
    for (int k0 = 0; k0 < NSEQ; k0 += 256) {
        __syncthreads();
        for (int i = t; i < 8 * 256; i += 64) {
            const int r = i >> 8, kp = i & 255;
            wsh[r][kp] = wts[((size_t)(b * NSEQ + q0 + r)) * NSEQ + k0 + kp];
        }
        __syncthreads();
        for (int kk = 0; kk < 256; kk += 8) {
            float vv[8][3];
            #pragma unroll
            for (int i = 0; i < 8; ++i) {
                const float* vrow = &vb[(size_t)(k0 + kk + i) * DD];
                vv[i][0] = vrow[t]; vv[i][1] = vrow[t + 64]; vv[i][2] = vrow[t + 128];
            }
            #pragma unroll
            for (int r = 0; r < 8; ++r) {
                float4 pa = *reinterpret_cast<const float4*>(&wsh[r][kk]);
                float4 pb = *reinterpret_cast<const float4*>(&wsh[r][kk + 4]);
                #pragma unroll
                for (int e = 0; e < 3; ++e) {
                    acc[r][e] += pa.x * vv[0][e] + pa.y * vv[1][e] + pa.z * vv[2][e] + pa.w * vv[3][e]
                               + pb.x * vv[4][e] + pb.y * vv[5][e] + pb.z * vv[6][e] + pb.w * vv[7][e];
                }
            }
        }
    }
    #pragma unroll
    for (int r = 0; r < 8; ++r) {
        float* mrow = &mid[((size_t)(b * NSEQ + q0 + r)) * DD];
        mrow[t] = acc[r][0]; mrow[t + 64] = acc[r][1]; mrow[t + 128] = acc[r][2];
    }
}

// final[r][o] = sum_e mid[r][e] * OW[o][e]; fp32 out to d_out[0..].
__global__ __launch_bounds__(192) void oproj_kernel(
        const float* __restrict__ x, const float* __restrict__ W,
        float* __restrict__ y) {
    __shared__ float xs[8][DD];
    const int r0 = blockIdx.x * 8;
    const int t  = threadIdx.x;
    for (int i = t; i < 8 * DD; i += 192)
        xs[i / DD][i % DD] = x[(size_t)r0 * DD + i];
    __syncthreads();

    float acc[8] = {0.f,0.f,0.f,0.f,0.f,0.f,0.f,0.f};
    const float* wrow = W + t * DD;
    #pragma unroll
    for (int c = 0; c < DD; c += 8) {
        float4 pa = *reinterpret_cast<const float4*>(wrow + c);
        float4 pb = *reinterpret_cast<const float4*>(wrow + c + 4);
        #pragma unroll
        for (int r = 0; r < 8; ++r) {
            const float* xr = &xs[r][c];
            acc[r] += pa.x*xr[0] + pa.y*xr[1] + pa.z*xr[2] + pa.w*xr[3]
                    + pb.x*xr[4] + pb.y*xr[5] + pb.z*xr[6] + pb.w*xr[7];
        }
    }
    #pragma unroll
    for (int r = 0; r < 8; ++r) y[(size_t)(r0 + r) * DD + t] = acc[r];
}

extern "C" void kernel_launch(void* const* d_in, const int* in_sizes, int n_in,
                              void* d_out, int out_size, void* d_ws, size_t ws_size,
                              hipStream_t stream) {
    const float* query = (const float*)d_in[0];
    const float* key   = (const float*)d_in[1];
    const float* value = (const float*)d_in[2];
    const float* mask  = (const float*)d_in[3];
    const float* bias  = (const float*)d_in[4];
    const float* qw    = (const float*)d_in[5];
    const float* kw    = (const float*)d_in[6];
    const float* vw    = (const float*)d_in[7];
    const float* ow    = (const float*)d_in[8];

    const size_t nrows = (size_t)NB * NSEQ;   // 16384
    float* dout = (float*)d_out;

    // workspace: q | k | v fp32 (37.75 MB). mid aliases q (dead after softmax).
    float* qf  = (float*)d_ws;
    float* kf  = qf + nrows * DD;
    float* vf  = kf + nrows * DD;
    float* mid = qf;

    proj_kernel<<<dim3(nrows / 8), 192, 0, stream>>>(query, qw, qf);
    proj_kernel<<<dim3(nrows / 8), 192, 0, stream>>>(key,   kw, kf);
    proj_kernel<<<dim3(nrows / 8), 192, 0, stream>>>(value, vw, vf);

    attn_softmax_kernel<<<dim3(NSEQ / 4, NB), 256, 0, stream>>>(
        qf, kf, bias, mask, dout);

    pv_kernel<<<dim3(NSEQ / 8, NB), 64, 0, stream>>>(dout, vf, mid);

    oproj_kernel<<<dim3(nrows / 8), 192, 0, stream>>>(mid, ow, dout);
}